// Round 10
// baseline (81.589 us; speedup 1.0000x reference)
//
#include <hip/hip_runtime.h>

// Wave forward: 16 channels, 208x208 window/channel, 48 steps, ONE persistent
// kernel. 6 phases x 8 substeps; boundaries sync the 3x3 tile neighborhood via
// agent-scope atomic flags; halo data moves via relaxed agent atomics.
// This round: (1) L/R stencil reads are ds_read_b64 (only 2 cols needed);
// (2) publish split: f_{J+6} rim issued after substep 6 (latency hidden under
// substep 7), f_{J+7} rim + single drain after substep 7.

typedef unsigned long long u64;

#define GN     512
#define NMASK  511
#define NCH    16
#define NT     48
#define NM     128
#define WW     208            // window size
#define WOFF   103            // source offset inside window
#define TI     52             // tile interior
#define TS     8              // substeps per phase
#define NPHASE 6
#define HALO   16             // 2*TS
#define LT     84             // tile width (TI + 2*HALO)
#define LTS    84             // LDS row stride
#define LDSE   (LTS*LT)       // 7056
#define WCELLS (WW*WW)        // 43264
#define NTH    448            // 7 waves
#define NACT   441            // 21x21 threads x 4x4 cells = 84^2
#define NBLK   256
#define FRAME_N 2304          // interior rim cells (52^2 - 20^2)
#define FRAME_A 1664          // rows 16-31,52-67 x cols 16-67
#define HALO_N  4352          // 84^2 - 52^2
#define HALO_TB 2688          // rows 0-15,68-83 x cols 0-83
#define NPULL   10            // ceil(HALO_N / NTH)

__device__ __forceinline__ float4 ld4(const float* p) { return *(const float4*)p; }
__device__ __forceinline__ void st4(float* p, float4 v) { *(float4*)p = v; }
__device__ __forceinline__ float2 ld2(const float* p) { return *(const float2*)p; }

__device__ __forceinline__ float kcoef(const float* __restrict__ x, int gi, int gj) {
    float xp;
    if (gi < 55 || gi >= 457 || gj < 55 || gj >= 457)
        xp = 1e-6f;                                   // ABC pad
    else if (gi >= 128 && gi < 384 && gj >= 128 && gj < 384)
        xp = x[(gi - 128) * 256 + (gj - 128)];
    else
        xp = 1.5f;                                    // bg pad
    float t = 0.2f * xp;
    return t * t;
}

// support-cone distance of a tile's 84^2 region to the source (channel-indep.)
__device__ __forceinline__ int tile_sdist(int ti, int tj) {
    int lo = ti * TI - HALO, hi = lo + LT - 1;
    int di = WOFF < lo ? lo - WOFF : (WOFF > hi ? WOFF - hi : 0);
    lo = tj * TI - HALO; hi = lo + LT - 1;
    int dj = WOFF < lo ? lo - WOFF : (WOFF > hi ? WOFF - hi : 0);
    return di > dj ? di : dj;
}
__device__ __forceinline__ bool tile_live(int ti, int tj, int ph) {
    return tile_sdist(ti, tj) <= 2 * (ph * TS + TS) + 4;
}

// frame (interior rim) linear index -> (row,col)
__device__ __forceinline__ void frame_rc(int q, int& row, int& col) {
    if (q < FRAME_A) {
        int rA = q / 52;
        row = 16 + (rA < 16 ? rA : rA + 20);
        col = 16 + (q - rA * 52);
    } else {
        int q2 = q - FRAME_A;
        int rB = q2 / 32;
        int c  = q2 - rB * 32;
        row = 32 + rB;
        col = 16 + (c < 16 ? c : c + 20);
    }
}

__global__ __launch_bounds__(NTH, 1)
void persist_kernel(const float* __restrict__ x,
                    const float* __restrict__ src,
                    const int* __restrict__ meas,
                    const int* __restrict__ trans,
                    int* __restrict__ flags,
                    float2* __restrict__ GA, float2* __restrict__ GB,
                    float* __restrict__ out)
{
    __shared__ float lds0[LDSE];
    __shared__ float lds1[LDSE];
    const int tid  = threadIdx.x;
    const int b    = blockIdx.x;
    const int r    = b & 15;          // channel -> all its tiles share b%8 (XCD)
    const int tile = b >> 4;
    const int tI   = tile >> 2, tJ = tile & 3;
    const int ri0  = tI * TI - HALO;
    const int rj0  = tJ * TI - HALO;

    const bool active = tid < NACT;
    const int ty = tid / 21, tx = tid - 21 * (tid / 21);
    const int li0 = 4 * ty, lj0 = 4 * tx;
    const bool inner = active && tx >= 4 && tx <= 16 && ty >= 4 && ty <= 16;

    // zero BOTH buffers (dead->live blocks rely on pristine-zero LDS)
    for (int q = tid; q < LDSE / 4; q += NTH) {
        st4(&lds0[q * 4], make_float4(0.f, 0.f, 0.f, 0.f));
        st4(&lds1[q * 4], make_float4(0.f, 0.f, 0.f, 0.f));
    }

    const int trv = trans[r];
    const int ox = (trv >> 9) - WOFF, oy = (trv & NMASK) - WOFF;

    float C[16], P[16], K[16];
    #pragma unroll
    for (int i = 0; i < 16; ++i) { C[i] = 0.f; P[i] = 0.f; K[i] = 0.f; }

    int offT2 = 0, offT1 = 0, offB1 = 0, offB2 = 0;
    int offLp[4] = {0,0,0,0}, offRp[4] = {0,0,0,0}, offC[4] = {0,0,0,0};
    unsigned smask = 0;
    if (active) {
        #pragma unroll
        for (int rr = 0; rr < 4; ++rr) {
            int wr = ri0 + li0 + rr;
            #pragma unroll
            for (int cc = 0; cc < 4; ++cc) {
                int wc = rj0 + lj0 + cc;
                K[rr*4+cc] = kcoef(x, (ox + wr) & NMASK, (oy + wc) & NMASK);
            }
        }
        int rT2 = li0 - 2 < 0 ? 0 : li0 - 2;
        int rT1 = li0 - 1 < 0 ? 0 : li0 - 1;
        int rB1 = li0 + 4 > LT - 1 ? LT - 1 : li0 + 4;
        int rB2 = li0 + 5 > LT - 1 ? LT - 1 : li0 + 5;
        offT2 = rT2 * LTS + lj0;  offT1 = rT1 * LTS + lj0;
        offB1 = rB1 * LTS + lj0;  offB2 = rB2 * LTS + lj0;
        #pragma unroll
        for (int rr = 0; rr < 4; ++rr) {
            int base = (li0 + rr) * LTS + lj0;
            offC[rr] = base;
            int ol = base - 2;  if (ol < 0) ol = 0;           // 8B aligned
            int orr = base + 4; if (orr > LDSE - 2) orr = LDSE - 2;
            offLp[rr] = ol; offRp[rr] = orr;
        }
        int si = (WOFF - ri0) - li0, sj = (WOFF - rj0) - lj0;
        if (si >= 0 && si < 4 && sj >= 0 && sj < 4) smask = 1u << (si * 4 + sj);
    }

    bool mvalid = false; int mlds = 0; float* mout = nullptr;
    if (tid < NM) {
        int mc = meas[tid];
        int mi = ((mc >> 9)    - ox) & NMASK;
        int mj = ((mc & NMASK) - oy) & NMASK;
        int li = mi - ri0, lj = mj - rj0;
        mvalid = (li >= HALO && li < HALO + TI && lj >= HALO && lj < HALO + TI);
        mlds = li * LTS + lj;
        mout = out + (size_t)(r * NM + tid) * NT;
    }

    __syncthreads();

    auto step1 = [&](float (&A)[16], float (&B)[16],
                     const float* rd, float* wb, float sval, int jj) {
        if (active) {
            float t2[4], t1[4], b1a[4], b2a[4];
            float4 v;
            v = ld4(rd + offT2); t2[0]=v.x;  t2[1]=v.y;  t2[2]=v.z;  t2[3]=v.w;
            v = ld4(rd + offT1); t1[0]=v.x;  t1[1]=v.y;  t1[2]=v.z;  t1[3]=v.w;
            v = ld4(rd + offB1); b1a[0]=v.x; b1a[1]=v.y; b1a[2]=v.z; b1a[3]=v.w;
            v = ld4(rd + offB2); b2a[0]=v.x; b2a[1]=v.y; b2a[2]=v.z; b2a[3]=v.w;
            float2 lp[4], rp[4];
            #pragma unroll
            for (int rr = 0; rr < 4; ++rr) {
                lp[rr] = ld2(rd + offLp[rr]);   // cols -2,-1
                rp[rr] = ld2(rd + offRp[rr]);   // cols +4,+5
            }
            #pragma unroll
            for (int rr = 0; rr < 4; ++rr) {
                float h[8];
                h[0]=lp[rr].x; h[1]=lp[rr].y;
                h[2]=B[rr*4+0]; h[3]=B[rr*4+1]; h[4]=B[rr*4+2]; h[5]=B[rr*4+3];
                h[6]=rp[rr].x; h[7]=rp[rr].y;
                #pragma unroll
                for (int cc = 0; cc < 4; ++cc) {
                    float vm2 = (rr == 0) ? t2[cc]  : (rr == 1) ? t1[cc]  : B[(rr-2)*4+cc];
                    float vm1 = (rr == 0) ? t1[cc]  : B[(rr-1)*4+cc];
                    float vp1 = (rr == 3) ? b1a[cc] : B[(rr+1)*4+cc];
                    float vp2 = (rr == 3) ? b2a[cc] : (rr == 2) ? b1a[cc] : B[(rr+2)*4+cc];
                    float c0  = h[cc+2];
                    float lap = (16.f * (h[cc+1] + h[cc+3] + vm1 + vp1)
                                 - (h[cc] + h[cc+4] + vm2 + vp2)
                                 - 60.f * c0) * (1.f / 12.f);
                    float pn = 2.f * c0 - A[rr*4+cc] + K[rr*4+cc] * lap;
                    if (smask & (1u << (rr*4+cc))) pn += sval;
                    A[rr*4+cc] = pn;
                }
                st4(wb + offC[rr],
                    make_float4(A[rr*4+0], A[rr*4+1], A[rr*4+2], A[rr*4+3]));
            }
        }
        __syncthreads();
        if (mvalid) mout[jj] = wb[mlds];
    };

    // publish one rim component (comp 0 = .x = newest level, 1 = .y = older)
    auto pubFrame = [&](const float* ldsrc, int comp, float2* Wp) {
        for (int q = tid; q < FRAME_N; q += NTH) {
            int row, col;
            frame_rc(q, row, col);
            int gw = (ri0 + row) * WW + (rj0 + col);
            int l  = row * LTS + col;
            __hip_atomic_store((float*)&Wp[gw] + comp, ldsrc[l],
                               __ATOMIC_RELAXED, __HIP_MEMORY_SCOPE_AGENT);
        }
    };

    for (int ph = 0; ph < NPHASE; ++ph) {
        const int J = ph * TS;
        const bool liveSelf = tile_live(tI, tJ, ph);
        float2* Wp = ((ph & 1) ? GB : GA) + (size_t)r * WCELLS;
        const bool bnd = ph < NPHASE - 1;
        if (liveSelf) {
            float sv[TS];
            #pragma unroll
            for (int s = 0; s < TS; ++s) sv[s] = 0.09f * src[J + s];
            step1(P, C, lds0, lds1, sv[0], J + 0);
            step1(C, P, lds1, lds0, sv[1], J + 1);
            step1(P, C, lds0, lds1, sv[2], J + 2);
            step1(C, P, lds1, lds0, sv[3], J + 3);
            step1(P, C, lds0, lds1, sv[4], J + 4);
            step1(C, P, lds1, lds0, sv[5], J + 5);
            step1(P, C, lds0, lds1, sv[6], J + 6);
            // f_{J+6} final in lds1 -> issue its rim now; drains under substep 7
            if (bnd) pubFrame(lds1, 1, Wp);
            step1(C, P, lds1, lds0, sv[7], J + 7);
            // lds0 = f_{J+7} (valid [16,68)^2), lds1 = f_{J+6}
        }
        if (bnd) {
            if (liveSelf) {       // second half of publish + single drain
                pubFrame(lds0, 0, Wp);
                asm volatile("s_waitcnt vmcnt(0)" ::: "memory");
            }
            __syncthreads();
            if (liveSelf && tid == 0)
                __hip_atomic_store(&flags[ph * NBLK + b], 1,
                                   __ATOMIC_RELAXED, __HIP_MEMORY_SCOPE_AGENT);
            const bool liveNext = tile_live(tI, tJ, ph + 1);
            if (liveNext && tid < 9 && tid != 4) {     // spin on live neighbors
                int nti = tI + tid / 3 - 1, ntj = tJ + tid % 3 - 1;
                if ((unsigned)nti < 4u && (unsigned)ntj < 4u &&
                    tile_live(nti, ntj, ph)) {
                    int* f = &flags[ph * NBLK + ((((nti << 2) | ntj) << 4) | r)];
                    while (!__hip_atomic_load(f, __ATOMIC_RELAXED,
                                              __HIP_MEMORY_SCOPE_AGENT)) {}
                }
            }
            __syncthreads();
            if (liveNext) {
                // batched pull: issue ALL loads (static reg indices), then write LDS
                u64 vv[NPULL]; int ll[NPULL];
                #pragma unroll
                for (int k = 0; k < NPULL; ++k) {
                    vv[k] = 0; ll[k] = -1;
                    int q = tid + k * NTH;
                    if (q < HALO_N) {
                        int row, col;
                        if (q < HALO_TB) {
                            int rT = q / 84;
                            row = rT < 16 ? rT : rT + 52;
                            col = q - rT * 84;
                        } else {
                            int q2 = q - HALO_TB;
                            int rM = q2 / 32;
                            int c  = q2 - rM * 32;
                            row = 16 + rM;
                            col = c < 16 ? c : c + 52;
                        }
                        ll[k] = row * LTS + col;
                        int nti = tI + (row < HALO ? -1 : (row >= HALO + TI ? 1 : 0));
                        int ntj = tJ + (col < HALO ? -1 : (col >= HALO + TI ? 1 : 0));
                        if ((unsigned)nti < 4u && (unsigned)ntj < 4u &&
                            tile_live(nti, ntj, ph)) {
                            int gw = (ri0 + row) * WW + (rj0 + col);
                            vv[k] = __hip_atomic_load((const u64*)&Wp[gw],
                                    __ATOMIC_RELAXED, __HIP_MEMORY_SCOPE_AGENT);
                        }
                    }
                }
                #pragma unroll
                for (int k = 0; k < NPULL; ++k) {
                    if (ll[k] >= 0) {
                        float2 f2; __builtin_memcpy(&f2, &vv[k], 8);
                        lds0[ll[k]] = f2.x;
                        lds1[ll[k]] = f2.y;
                    }
                }
                __syncthreads();
                if (active && !inner) {   // ring threads refill regs from LDS
                    #pragma unroll
                    for (int rr = 0; rr < 4; ++rr) {
                        float4 vc = ld4(&lds0[offC[rr]]);
                        float4 vp = ld4(&lds1[offC[rr]]);
                        C[rr*4+0]=vc.x; C[rr*4+1]=vc.y; C[rr*4+2]=vc.z; C[rr*4+3]=vc.w;
                        P[rr*4+0]=vp.x; P[rr*4+1]=vp.y; P[rr*4+2]=vp.z; P[rr*4+3]=vp.w;
                    }
                }
            }
        }
    }
}

extern "C" void kernel_launch(void* const* d_in, const int* in_sizes, int n_in,
                              void* d_out, int out_size, void* d_ws, size_t ws_size,
                              hipStream_t stream)
{
    const float* x     = (const float*)d_in[0];
    const float* src   = (const float*)d_in[1];
    const int*   meas  = (const int*)d_in[2];
    const int*   trans = (const int*)d_in[3];
    float* outp = (float*)d_out;

    int*    flags = (int*)d_ws;                         // NPHASE*NBLK ints
    float2* GA = (float2*)((char*)d_ws + 8192);
    float2* GB = GA + (size_t)NCH * WCELLS;

    hipMemsetAsync(flags, 0, NPHASE * NBLK * sizeof(int), stream);
    hipMemsetAsync(outp, 0, (size_t)out_size * sizeof(float), stream);

    persist_kernel<<<NBLK, NTH, 0, stream>>>(x, src, meas, trans, flags,
                                             GA, GB, outp);
}

// Round 11
// 80.910 us; speedup vs baseline: 1.0084x; 1.0084x over previous
//
#include <hip/hip_runtime.h>

// Wave forward: 16 channels, 208x208 window/channel, 48 steps, ONE persistent
// kernel. 6 phases x 8 substeps; boundaries sync the 3x3 tile neighborhood via
// agent-scope atomic flags; halo data moves as packed float2 via 64-bit
// relaxed agent atomics. Register-blocked 4x4 cells/thread; LDS ping-pong.
// This round: publish is REGISTER-DIRECT -- after substep 7 the 144 frame
// threads store their 16 cells (C=f_{J+7}, P=f_{J+6}) as packed u64 straight
// from registers (no LDS re-read pass, single-transaction packed writes).

typedef unsigned long long u64;

#define GN     512
#define NMASK  511
#define NCH    16
#define NT     48
#define NM     128
#define WW     208            // window size
#define WOFF   103            // source offset inside window
#define TI     52             // tile interior
#define TS     8              // substeps per phase
#define NPHASE 6
#define HALO   16             // 2*TS
#define LT     84             // tile width (TI + 2*HALO)
#define LTS    84             // LDS row stride
#define LDSE   (LTS*LT)       // 7056
#define WCELLS (WW*WW)        // 43264
#define NTH    448            // 7 waves
#define NACT   441            // 21x21 threads x 4x4 cells = 84^2
#define NBLK   256
#define HALO_N  4352          // 84^2 - 52^2
#define HALO_TB 2688          // rows 0-15,68-83 x cols 0-83
#define NPULL   10            // ceil(HALO_N / NTH)

__device__ __forceinline__ float4 ld4(const float* p) { return *(const float4*)p; }
__device__ __forceinline__ void st4(float* p, float4 v) { *(float4*)p = v; }
__device__ __forceinline__ float2 ld2(const float* p) { return *(const float2*)p; }

__device__ __forceinline__ float kcoef(const float* __restrict__ x, int gi, int gj) {
    float xp;
    if (gi < 55 || gi >= 457 || gj < 55 || gj >= 457)
        xp = 1e-6f;                                   // ABC pad
    else if (gi >= 128 && gi < 384 && gj >= 128 && gj < 384)
        xp = x[(gi - 128) * 256 + (gj - 128)];
    else
        xp = 1.5f;                                    // bg pad
    float t = 0.2f * xp;
    return t * t;
}

// support-cone distance of a tile's 84^2 region to the source (channel-indep.)
__device__ __forceinline__ int tile_sdist(int ti, int tj) {
    int lo = ti * TI - HALO, hi = lo + LT - 1;
    int di = WOFF < lo ? lo - WOFF : (WOFF > hi ? WOFF - hi : 0);
    lo = tj * TI - HALO; hi = lo + LT - 1;
    int dj = WOFF < lo ? lo - WOFF : (WOFF > hi ? WOFF - hi : 0);
    return di > dj ? di : dj;
}
__device__ __forceinline__ bool tile_live(int ti, int tj, int ph) {
    return tile_sdist(ti, tj) <= 2 * (ph * TS + TS) + 4;
}

__global__ __launch_bounds__(NTH, 1)
void persist_kernel(const float* __restrict__ x,
                    const float* __restrict__ src,
                    const int* __restrict__ meas,
                    const int* __restrict__ trans,
                    int* __restrict__ flags,
                    float2* __restrict__ GA, float2* __restrict__ GB,
                    float* __restrict__ out)
{
    __shared__ float lds0[LDSE];
    __shared__ float lds1[LDSE];
    const int tid  = threadIdx.x;
    const int b    = blockIdx.x;
    const int r    = b & 15;          // channel
    const int tile = b >> 4;
    const int tI   = tile >> 2, tJ = tile & 3;
    const int ri0  = tI * TI - HALO;
    const int rj0  = tJ * TI - HALO;

    const bool active = tid < NACT;
    const int ty = tid / 21, tx = tid - 21 * (tid / 21);
    const int li0 = 4 * ty, lj0 = 4 * tx;
    const bool inner = active && tx >= 4 && tx <= 16 && ty >= 4 && ty <= 16;
    const bool core  = ty >= 8 && ty <= 12 && tx >= 8 && tx <= 12;  // 20^2 core
    const bool frame = inner && !core;   // 144 threads own the 2304-cell rim

    // zero BOTH buffers (dead->live blocks rely on pristine-zero LDS)
    for (int q = tid; q < LDSE / 4; q += NTH) {
        st4(&lds0[q * 4], make_float4(0.f, 0.f, 0.f, 0.f));
        st4(&lds1[q * 4], make_float4(0.f, 0.f, 0.f, 0.f));
    }

    const int trv = trans[r];
    const int ox = (trv >> 9) - WOFF, oy = (trv & NMASK) - WOFF;

    float C[16], P[16], K[16];
    #pragma unroll
    for (int i = 0; i < 16; ++i) { C[i] = 0.f; P[i] = 0.f; K[i] = 0.f; }

    int offT2 = 0, offT1 = 0, offB1 = 0, offB2 = 0;
    int offLp[4] = {0,0,0,0}, offRp[4] = {0,0,0,0}, offC[4] = {0,0,0,0};
    unsigned smask = 0;
    if (active) {
        #pragma unroll
        for (int rr = 0; rr < 4; ++rr) {
            int wr = ri0 + li0 + rr;
            #pragma unroll
            for (int cc = 0; cc < 4; ++cc) {
                int wc = rj0 + lj0 + cc;
                K[rr*4+cc] = kcoef(x, (ox + wr) & NMASK, (oy + wc) & NMASK);
            }
        }
        int rT2 = li0 - 2 < 0 ? 0 : li0 - 2;
        int rT1 = li0 - 1 < 0 ? 0 : li0 - 1;
        int rB1 = li0 + 4 > LT - 1 ? LT - 1 : li0 + 4;
        int rB2 = li0 + 5 > LT - 1 ? LT - 1 : li0 + 5;
        offT2 = rT2 * LTS + lj0;  offT1 = rT1 * LTS + lj0;
        offB1 = rB1 * LTS + lj0;  offB2 = rB2 * LTS + lj0;
        #pragma unroll
        for (int rr = 0; rr < 4; ++rr) {
            int base = (li0 + rr) * LTS + lj0;
            offC[rr] = base;
            int ol = base - 2;  if (ol < 0) ol = 0;           // 8B aligned
            int orr = base + 4; if (orr > LDSE - 2) orr = LDSE - 2;
            offLp[rr] = ol; offRp[rr] = orr;
        }
        int si = (WOFF - ri0) - li0, sj = (WOFF - rj0) - lj0;
        if (si >= 0 && si < 4 && sj >= 0 && sj < 4) smask = 1u << (si * 4 + sj);
    }

    bool mvalid = false; int mlds = 0; float* mout = nullptr;
    if (tid < NM) {
        int mc = meas[tid];
        int mi = ((mc >> 9)    - ox) & NMASK;
        int mj = ((mc & NMASK) - oy) & NMASK;
        int li = mi - ri0, lj = mj - rj0;
        mvalid = (li >= HALO && li < HALO + TI && lj >= HALO && lj < HALO + TI);
        mlds = li * LTS + lj;
        mout = out + (size_t)(r * NM + tid) * NT;
    }

    __syncthreads();

    auto step1 = [&](float (&A)[16], float (&B)[16],
                     const float* rd, float* wb, float sval, int jj) {
        if (active) {
            float t2[4], t1[4], b1a[4], b2a[4];
            float4 v;
            v = ld4(rd + offT2); t2[0]=v.x;  t2[1]=v.y;  t2[2]=v.z;  t2[3]=v.w;
            v = ld4(rd + offT1); t1[0]=v.x;  t1[1]=v.y;  t1[2]=v.z;  t1[3]=v.w;
            v = ld4(rd + offB1); b1a[0]=v.x; b1a[1]=v.y; b1a[2]=v.z; b1a[3]=v.w;
            v = ld4(rd + offB2); b2a[0]=v.x; b2a[1]=v.y; b2a[2]=v.z; b2a[3]=v.w;
            float2 lp[4], rp[4];
            #pragma unroll
            for (int rr = 0; rr < 4; ++rr) {
                lp[rr] = ld2(rd + offLp[rr]);   // cols -2,-1
                rp[rr] = ld2(rd + offRp[rr]);   // cols +4,+5
            }
            #pragma unroll
            for (int rr = 0; rr < 4; ++rr) {
                float h[8];
                h[0]=lp[rr].x; h[1]=lp[rr].y;
                h[2]=B[rr*4+0]; h[3]=B[rr*4+1]; h[4]=B[rr*4+2]; h[5]=B[rr*4+3];
                h[6]=rp[rr].x; h[7]=rp[rr].y;
                #pragma unroll
                for (int cc = 0; cc < 4; ++cc) {
                    float vm2 = (rr == 0) ? t2[cc]  : (rr == 1) ? t1[cc]  : B[(rr-2)*4+cc];
                    float vm1 = (rr == 0) ? t1[cc]  : B[(rr-1)*4+cc];
                    float vp1 = (rr == 3) ? b1a[cc] : B[(rr+1)*4+cc];
                    float vp2 = (rr == 3) ? b2a[cc] : (rr == 2) ? b1a[cc] : B[(rr+2)*4+cc];
                    float c0  = h[cc+2];
                    float lap = (16.f * (h[cc+1] + h[cc+3] + vm1 + vp1)
                                 - (h[cc] + h[cc+4] + vm2 + vp2)
                                 - 60.f * c0) * (1.f / 12.f);
                    float pn = 2.f * c0 - A[rr*4+cc] + K[rr*4+cc] * lap;
                    if (smask & (1u << (rr*4+cc))) pn += sval;
                    A[rr*4+cc] = pn;
                }
                st4(wb + offC[rr],
                    make_float4(A[rr*4+0], A[rr*4+1], A[rr*4+2], A[rr*4+3]));
            }
        }
        __syncthreads();
        if (mvalid) mout[jj] = wb[mlds];
    };

    for (int ph = 0; ph < NPHASE; ++ph) {
        const int J = ph * TS;
        const bool liveSelf = tile_live(tI, tJ, ph);
        float2* Wp = ((ph & 1) ? GB : GA) + (size_t)r * WCELLS;
        const bool bnd = ph < NPHASE - 1;
        if (liveSelf) {
            float sv[TS];
            #pragma unroll
            for (int s = 0; s < TS; ++s) sv[s] = 0.09f * src[J + s];
            step1(P, C, lds0, lds1, sv[0], J + 0);
            step1(C, P, lds1, lds0, sv[1], J + 1);
            step1(P, C, lds0, lds1, sv[2], J + 2);
            step1(C, P, lds1, lds0, sv[3], J + 3);
            step1(P, C, lds0, lds1, sv[4], J + 4);
            step1(C, P, lds1, lds0, sv[5], J + 5);
            step1(P, C, lds0, lds1, sv[6], J + 6);
            step1(C, P, lds1, lds0, sv[7], J + 7);
            // C = f_{J+7}, P = f_{J+6}; lds0 = f_{J+7}, lds1 = f_{J+6}
        }
        if (bnd) {
            if (liveSelf && frame) {
                // register-direct publish: 16 packed u64 stores from C/P
                #pragma unroll
                for (int rr = 0; rr < 4; ++rr) {
                    int gwr = (ri0 + li0 + rr) * WW + (rj0 + lj0);
                    #pragma unroll
                    for (int cc = 0; cc < 4; ++cc) {
                        float2 f2 = make_float2(C[rr*4+cc], P[rr*4+cc]);
                        u64 v; __builtin_memcpy(&v, &f2, 8);
                        __hip_atomic_store((u64*)&Wp[gwr + cc], v,
                                           __ATOMIC_RELAXED, __HIP_MEMORY_SCOPE_AGENT);
                    }
                }
            }
            asm volatile("s_waitcnt vmcnt(0)" ::: "memory");   // my stores at MALL
            __syncthreads();                                    // whole block done
            if (liveSelf && tid == 0)
                __hip_atomic_store(&flags[ph * NBLK + b], 1,
                                   __ATOMIC_RELAXED, __HIP_MEMORY_SCOPE_AGENT);
            const bool liveNext = tile_live(tI, tJ, ph + 1);
            if (liveNext && tid < 9 && tid != 4) {     // spin on live neighbors
                int nti = tI + tid / 3 - 1, ntj = tJ + tid % 3 - 1;
                if ((unsigned)nti < 4u && (unsigned)ntj < 4u &&
                    tile_live(nti, ntj, ph)) {
                    int* f = &flags[ph * NBLK + ((((nti << 2) | ntj) << 4) | r)];
                    while (!__hip_atomic_load(f, __ATOMIC_RELAXED,
                                              __HIP_MEMORY_SCOPE_AGENT)) {}
                }
            }
            __syncthreads();
            if (liveNext) {
                // batched pull: issue ALL loads (static reg indices), then write LDS
                u64 vv[NPULL]; int ll[NPULL];
                #pragma unroll
                for (int k = 0; k < NPULL; ++k) {
                    vv[k] = 0; ll[k] = -1;
                    int q = tid + k * NTH;
                    if (q < HALO_N) {
                        int row, col;
                        if (q < HALO_TB) {
                            int rT = q / 84;
                            row = rT < 16 ? rT : rT + 52;
                            col = q - rT * 84;
                        } else {
                            int q2 = q - HALO_TB;
                            int rM = q2 / 32;
                            int c  = q2 - rM * 32;
                            row = 16 + rM;
                            col = c < 16 ? c : c + 52;
                        }
                        ll[k] = row * LTS + col;
                        int nti = tI + (row < HALO ? -1 : (row >= HALO + TI ? 1 : 0));
                        int ntj = tJ + (col < HALO ? -1 : (col >= HALO + TI ? 1 : 0));
                        if ((unsigned)nti < 4u && (unsigned)ntj < 4u &&
                            tile_live(nti, ntj, ph)) {
                            int gw = (ri0 + row) * WW + (rj0 + col);
                            vv[k] = __hip_atomic_load((const u64*)&Wp[gw],
                                    __ATOMIC_RELAXED, __HIP_MEMORY_SCOPE_AGENT);
                        }
                    }
                }
                #pragma unroll
                for (int k = 0; k < NPULL; ++k) {
                    if (ll[k] >= 0) {
                        float2 f2; __builtin_memcpy(&f2, &vv[k], 8);
                        lds0[ll[k]] = f2.x;
                        lds1[ll[k]] = f2.y;
                    }
                }
                __syncthreads();
                if (active && !inner) {   // ring threads refill regs from LDS
                    #pragma unroll
                    for (int rr = 0; rr < 4; ++rr) {
                        float4 vc = ld4(&lds0[offC[rr]]);
                        float4 vp = ld4(&lds1[offC[rr]]);
                        C[rr*4+0]=vc.x; C[rr*4+1]=vc.y; C[rr*4+2]=vc.z; C[rr*4+3]=vc.w;
                        P[rr*4+0]=vp.x; P[rr*4+1]=vp.y; P[rr*4+2]=vp.z; P[rr*4+3]=vp.w;
                    }
                }
            }
        }
    }
}

extern "C" void kernel_launch(void* const* d_in, const int* in_sizes, int n_in,
                              void* d_out, int out_size, void* d_ws, size_t ws_size,
                              hipStream_t stream)
{
    const float* x     = (const float*)d_in[0];
    const float* src   = (const float*)d_in[1];
    const int*   meas  = (const int*)d_in[2];
    const int*   trans = (const int*)d_in[3];
    float* outp = (float*)d_out;

    int*    flags = (int*)d_ws;                         // NPHASE*NBLK ints
    float2* GA = (float2*)((char*)d_ws + 8192);
    float2* GB = GA + (size_t)NCH * WCELLS;

    hipMemsetAsync(flags, 0, NPHASE * NBLK * sizeof(int), stream);
    hipMemsetAsync(outp, 0, (size_t)out_size * sizeof(float), stream);

    persist_kernel<<<NBLK, NTH, 0, stream>>>(x, src, meas, trans, flags,
                                             GA, GB, outp);
}

// Round 12
// 71.180 us; speedup vs baseline: 1.1462x; 1.1367x over previous
//
#include <hip/hip_runtime.h>

// Wave forward: 16 channels, 208x208 window/channel, 48 steps, ONE persistent
// kernel. 6 phases x 8 substeps; boundaries sync the 3x3 tile neighborhood via
// agent-scope atomic flags. Halo exchange is FP16-PACKED: each u64 carries
// (C,P) x 2 col-adjacent cells -> half the transactions and half the bytes of
// round 9's float2 scheme. Publish is LDS-sourced and lane-coalesced (r9
// form; r11's register-direct scatter regressed). Interior state stays fp32.

typedef unsigned long long u64;

#define GN     512
#define NMASK  511
#define NCH    16
#define NT     48
#define NM     128
#define WW     208            // window size
#define WOFF   103            // source offset inside window
#define TI     52             // tile interior
#define TS     8              // substeps per phase
#define NPHASE 6
#define HALO   16             // 2*TS
#define LT     84             // tile width (TI + 2*HALO)
#define LTS    84             // LDS row stride
#define LDSE   (LTS*LT)       // 7056
#define WCELLS (WW*WW)        // 43264
#define NTH    448            // 7 waves
#define NACT   441            // 21x21 threads x 4x4 cells = 84^2
#define NBLK   256
#define FPAIR  1152           // frame cell-pairs (2304/2)
#define FPAIR_A 832           // rows 16-31,52-67 x cols 16-67 (26 pairs/row)
#define NPAIR  2176           // halo cell-pairs (4352/2)
#define NPAIR_TB 1344         // rows 0-15,68-83 x 42 pairs/row
#define NPULL  5              // ceil(NPAIR / NTH)

__device__ __forceinline__ float4 ld4(const float* p) { return *(const float4*)p; }
__device__ __forceinline__ void st4(float* p, float4 v) { *(float4*)p = v; }
__device__ __forceinline__ float2 ld2(const float* p) { return *(const float2*)p; }

__device__ __forceinline__ unsigned pack2(float c, float p) {
    _Float16 hc = (_Float16)c, hp = (_Float16)p;
    unsigned short uc, up;
    __builtin_memcpy(&uc, &hc, 2); __builtin_memcpy(&up, &hp, 2);
    return (unsigned)uc | ((unsigned)up << 16);
}
__device__ __forceinline__ float2 unpack2(unsigned v) {   // -> (C, P)
    unsigned short uc = (unsigned short)(v & 0xffffu), up = (unsigned short)(v >> 16);
    _Float16 hc, hp;
    __builtin_memcpy(&hc, &uc, 2); __builtin_memcpy(&hp, &up, 2);
    return make_float2((float)hc, (float)hp);
}

__device__ __forceinline__ float kcoef(const float* __restrict__ x, int gi, int gj) {
    float xp;
    if (gi < 55 || gi >= 457 || gj < 55 || gj >= 457)
        xp = 1e-6f;                                   // ABC pad
    else if (gi >= 128 && gi < 384 && gj >= 128 && gj < 384)
        xp = x[(gi - 128) * 256 + (gj - 128)];
    else
        xp = 1.5f;                                    // bg pad
    float t = 0.2f * xp;
    return t * t;
}

// support-cone distance of a tile's 84^2 region to the source (channel-indep.)
__device__ __forceinline__ int tile_sdist(int ti, int tj) {
    int lo = ti * TI - HALO, hi = lo + LT - 1;
    int di = WOFF < lo ? lo - WOFF : (WOFF > hi ? WOFF - hi : 0);
    lo = tj * TI - HALO; hi = lo + LT - 1;
    int dj = WOFF < lo ? lo - WOFF : (WOFF > hi ? WOFF - hi : 0);
    return di > dj ? di : dj;
}
__device__ __forceinline__ bool tile_live(int ti, int tj, int ph) {
    return tile_sdist(ti, tj) <= 2 * (ph * TS + TS) + 4;
}

__global__ __launch_bounds__(NTH, 1)
void persist_kernel(const float* __restrict__ x,
                    const float* __restrict__ src,
                    const int* __restrict__ meas,
                    const int* __restrict__ trans,
                    int* __restrict__ flags,
                    unsigned* __restrict__ GA, unsigned* __restrict__ GB,
                    float* __restrict__ out)
{
    __shared__ float lds0[LDSE];
    __shared__ float lds1[LDSE];
    const int tid  = threadIdx.x;
    const int b    = blockIdx.x;
    const int r    = b & 15;          // channel
    const int tile = b >> 4;
    const int tI   = tile >> 2, tJ = tile & 3;
    const int ri0  = tI * TI - HALO;
    const int rj0  = tJ * TI - HALO;

    const bool active = tid < NACT;
    const int ty = tid / 21, tx = tid - 21 * (tid / 21);
    const int li0 = 4 * ty, lj0 = 4 * tx;
    const bool inner = active && tx >= 4 && tx <= 16 && ty >= 4 && ty <= 16;

    // zero BOTH buffers (dead->live blocks rely on pristine-zero LDS)
    for (int q = tid; q < LDSE / 4; q += NTH) {
        st4(&lds0[q * 4], make_float4(0.f, 0.f, 0.f, 0.f));
        st4(&lds1[q * 4], make_float4(0.f, 0.f, 0.f, 0.f));
    }

    const int trv = trans[r];
    const int ox = (trv >> 9) - WOFF, oy = (trv & NMASK) - WOFF;

    float C[16], P[16], K[16];
    #pragma unroll
    for (int i = 0; i < 16; ++i) { C[i] = 0.f; P[i] = 0.f; K[i] = 0.f; }

    int offT2 = 0, offT1 = 0, offB1 = 0, offB2 = 0;
    int offLp[4] = {0,0,0,0}, offRp[4] = {0,0,0,0}, offC[4] = {0,0,0,0};
    unsigned smask = 0;
    if (active) {
        #pragma unroll
        for (int rr = 0; rr < 4; ++rr) {
            int wr = ri0 + li0 + rr;
            #pragma unroll
            for (int cc = 0; cc < 4; ++cc) {
                int wc = rj0 + lj0 + cc;
                K[rr*4+cc] = kcoef(x, (ox + wr) & NMASK, (oy + wc) & NMASK);
            }
        }
        int rT2 = li0 - 2 < 0 ? 0 : li0 - 2;
        int rT1 = li0 - 1 < 0 ? 0 : li0 - 1;
        int rB1 = li0 + 4 > LT - 1 ? LT - 1 : li0 + 4;
        int rB2 = li0 + 5 > LT - 1 ? LT - 1 : li0 + 5;
        offT2 = rT2 * LTS + lj0;  offT1 = rT1 * LTS + lj0;
        offB1 = rB1 * LTS + lj0;  offB2 = rB2 * LTS + lj0;
        #pragma unroll
        for (int rr = 0; rr < 4; ++rr) {
            int base = (li0 + rr) * LTS + lj0;
            offC[rr] = base;
            int ol = base - 2;  if (ol < 0) ol = 0;           // 8B aligned
            int orr = base + 4; if (orr > LDSE - 2) orr = LDSE - 2;
            offLp[rr] = ol; offRp[rr] = orr;
        }
        int si = (WOFF - ri0) - li0, sj = (WOFF - rj0) - lj0;
        if (si >= 0 && si < 4 && sj >= 0 && sj < 4) smask = 1u << (si * 4 + sj);
    }

    bool mvalid = false; int mlds = 0; float* mout = nullptr;
    if (tid < NM) {
        int mc = meas[tid];
        int mi = ((mc >> 9)    - ox) & NMASK;
        int mj = ((mc & NMASK) - oy) & NMASK;
        int li = mi - ri0, lj = mj - rj0;
        mvalid = (li >= HALO && li < HALO + TI && lj >= HALO && lj < HALO + TI);
        mlds = li * LTS + lj;
        mout = out + (size_t)(r * NM + tid) * NT;
    }

    __syncthreads();

    auto step1 = [&](float (&A)[16], float (&B)[16],
                     const float* rd, float* wb, float sval, int jj) {
        if (active) {
            float t2[4], t1[4], b1a[4], b2a[4];
            float4 v;
            v = ld4(rd + offT2); t2[0]=v.x;  t2[1]=v.y;  t2[2]=v.z;  t2[3]=v.w;
            v = ld4(rd + offT1); t1[0]=v.x;  t1[1]=v.y;  t1[2]=v.z;  t1[3]=v.w;
            v = ld4(rd + offB1); b1a[0]=v.x; b1a[1]=v.y; b1a[2]=v.z; b1a[3]=v.w;
            v = ld4(rd + offB2); b2a[0]=v.x; b2a[1]=v.y; b2a[2]=v.z; b2a[3]=v.w;
            float2 lp[4], rp[4];
            #pragma unroll
            for (int rr = 0; rr < 4; ++rr) {
                lp[rr] = ld2(rd + offLp[rr]);   // cols -2,-1
                rp[rr] = ld2(rd + offRp[rr]);   // cols +4,+5
            }
            #pragma unroll
            for (int rr = 0; rr < 4; ++rr) {
                float h[8];
                h[0]=lp[rr].x; h[1]=lp[rr].y;
                h[2]=B[rr*4+0]; h[3]=B[rr*4+1]; h[4]=B[rr*4+2]; h[5]=B[rr*4+3];
                h[6]=rp[rr].x; h[7]=rp[rr].y;
                #pragma unroll
                for (int cc = 0; cc < 4; ++cc) {
                    float vm2 = (rr == 0) ? t2[cc]  : (rr == 1) ? t1[cc]  : B[(rr-2)*4+cc];
                    float vm1 = (rr == 0) ? t1[cc]  : B[(rr-1)*4+cc];
                    float vp1 = (rr == 3) ? b1a[cc] : B[(rr+1)*4+cc];
                    float vp2 = (rr == 3) ? b2a[cc] : (rr == 2) ? b1a[cc] : B[(rr+2)*4+cc];
                    float c0  = h[cc+2];
                    float lap = (16.f * (h[cc+1] + h[cc+3] + vm1 + vp1)
                                 - (h[cc] + h[cc+4] + vm2 + vp2)
                                 - 60.f * c0) * (1.f / 12.f);
                    float pn = 2.f * c0 - A[rr*4+cc] + K[rr*4+cc] * lap;
                    if (smask & (1u << (rr*4+cc))) pn += sval;
                    A[rr*4+cc] = pn;
                }
                st4(wb + offC[rr],
                    make_float4(A[rr*4+0], A[rr*4+1], A[rr*4+2], A[rr*4+3]));
            }
        }
        __syncthreads();
        if (mvalid) mout[jj] = wb[mlds];
    };

    for (int ph = 0; ph < NPHASE; ++ph) {
        const int J = ph * TS;
        const bool liveSelf = tile_live(tI, tJ, ph);
        unsigned* Wp = ((ph & 1) ? GB : GA) + (size_t)r * WCELLS;
        const bool bnd = ph < NPHASE - 1;
        if (liveSelf) {
            float sv[TS];
            #pragma unroll
            for (int s = 0; s < TS; ++s) sv[s] = 0.09f * src[J + s];
            step1(P, C, lds0, lds1, sv[0], J + 0);
            step1(C, P, lds1, lds0, sv[1], J + 1);
            step1(P, C, lds0, lds1, sv[2], J + 2);
            step1(C, P, lds1, lds0, sv[3], J + 3);
            step1(P, C, lds0, lds1, sv[4], J + 4);
            step1(C, P, lds1, lds0, sv[5], J + 5);
            step1(P, C, lds0, lds1, sv[6], J + 6);
            step1(C, P, lds1, lds0, sv[7], J + 7);
            // lds0 = f_{J+7} (valid [16,68)^2), lds1 = f_{J+6}
        }
        if (bnd) {
            if (liveSelf) {   // publish frame as fp16-packed cell pairs
                for (int pf = tid; pf < FPAIR; pf += NTH) {
                    int row, col;
                    if (pf < FPAIR_A) {
                        int rA = pf / 26;
                        row = 16 + (rA < 16 ? rA : rA + 20);
                        col = 16 + 2 * (pf - 26 * rA);
                    } else {
                        int p2 = pf - FPAIR_A;
                        int rB = p2 / 16;
                        int c  = p2 - 16 * rB;
                        row = 32 + rB;
                        col = c < 8 ? 16 + 2 * c : 2 * c + 36;   // 52..66
                    }
                    int l  = row * LTS + col;
                    unsigned lo = pack2(lds0[l],     lds1[l]);
                    unsigned hi = pack2(lds0[l + 1], lds1[l + 1]);
                    u64 v = (u64)lo | ((u64)hi << 32);
                    int gw = (ri0 + row) * WW + (rj0 + col);     // even
                    __hip_atomic_store((u64*)&Wp[gw], v,
                                       __ATOMIC_RELAXED, __HIP_MEMORY_SCOPE_AGENT);
                }
                asm volatile("s_waitcnt vmcnt(0)" ::: "memory");
            }
            __syncthreads();
            if (liveSelf && tid == 0)
                __hip_atomic_store(&flags[ph * NBLK + b], 1,
                                   __ATOMIC_RELAXED, __HIP_MEMORY_SCOPE_AGENT);
            const bool liveNext = tile_live(tI, tJ, ph + 1);
            if (liveNext && tid < 9 && tid != 4) {     // spin on live neighbors
                int nti = tI + tid / 3 - 1, ntj = tJ + tid % 3 - 1;
                if ((unsigned)nti < 4u && (unsigned)ntj < 4u &&
                    tile_live(nti, ntj, ph)) {
                    int* f = &flags[ph * NBLK + ((((nti << 2) | ntj) << 4) | r)];
                    while (!__hip_atomic_load(f, __ATOMIC_RELAXED,
                                              __HIP_MEMORY_SCOPE_AGENT)) {}
                }
            }
            __syncthreads();
            if (liveNext) {
                // batched pull of halo cell-pairs (static reg indices)
                u64 vv[NPULL]; int ll[NPULL];
                #pragma unroll
                for (int k = 0; k < NPULL; ++k) {
                    vv[k] = 0; ll[k] = -1;
                    int p = tid + k * NTH;
                    if (p < NPAIR) {
                        int row, col;
                        if (p < NPAIR_TB) {
                            int rT = p / 42;
                            row = rT < 16 ? rT : rT + 52;
                            col = 2 * (p - 42 * rT);
                        } else {
                            int p2 = p - NPAIR_TB;
                            int rM = p2 / 16;
                            int c  = p2 - 16 * rM;
                            row = 16 + rM;
                            col = c < 8 ? 2 * c : 2 * c + 52;    // 68..82
                        }
                        ll[k] = row * LTS + col;
                        int nti = tI + (row < HALO ? -1 : (row >= HALO + TI ? 1 : 0));
                        int ntj = tJ + (col < HALO ? -1 : (col >= HALO + TI ? 1 : 0));
                        if ((unsigned)nti < 4u && (unsigned)ntj < 4u &&
                            tile_live(nti, ntj, ph)) {
                            int gw = (ri0 + row) * WW + (rj0 + col);
                            vv[k] = __hip_atomic_load((const u64*)&Wp[gw],
                                    __ATOMIC_RELAXED, __HIP_MEMORY_SCOPE_AGENT);
                        }
                    }
                }
                #pragma unroll
                for (int k = 0; k < NPULL; ++k) {
                    if (ll[k] >= 0) {
                        float2 a = unpack2((unsigned)(vv[k] & 0xffffffffu));
                        float2 bb = unpack2((unsigned)(vv[k] >> 32));
                        lds0[ll[k]]     = a.x;  lds1[ll[k]]     = a.y;
                        lds0[ll[k] + 1] = bb.x; lds1[ll[k] + 1] = bb.y;
                    }
                }
                __syncthreads();
                if (active && !inner) {   // ring threads refill regs from LDS
                    #pragma unroll
                    for (int rr = 0; rr < 4; ++rr) {
                        float4 vc = ld4(&lds0[offC[rr]]);
                        float4 vp = ld4(&lds1[offC[rr]]);
                        C[rr*4+0]=vc.x; C[rr*4+1]=vc.y; C[rr*4+2]=vc.z; C[rr*4+3]=vc.w;
                        P[rr*4+0]=vp.x; P[rr*4+1]=vp.y; P[rr*4+2]=vp.z; P[rr*4+3]=vp.w;
                    }
                }
            }
        }
    }
}

extern "C" void kernel_launch(void* const* d_in, const int* in_sizes, int n_in,
                              void* d_out, int out_size, void* d_ws, size_t ws_size,
                              hipStream_t stream)
{
    const float* x     = (const float*)d_in[0];
    const float* src   = (const float*)d_in[1];
    const int*   meas  = (const int*)d_in[2];
    const int*   trans = (const int*)d_in[3];
    float* outp = (float*)d_out;

    int*      flags = (int*)d_ws;                       // NPHASE*NBLK ints
    unsigned* GA = (unsigned*)((char*)d_ws + 8192);
    unsigned* GB = GA + (size_t)NCH * WCELLS;

    hipMemsetAsync(flags, 0, NPHASE * NBLK * sizeof(int), stream);
    hipMemsetAsync(outp, 0, (size_t)out_size * sizeof(float), stream);

    persist_kernel<<<NBLK, NTH, 0, stream>>>(x, src, meas, trans, flags,
                                             GA, GB, outp);
}

// Round 13
// 71.048 us; speedup vs baseline: 1.1484x; 1.0019x over previous
//
#include <hip/hip_runtime.h>

// Wave forward: 16 channels, 208x208 window/channel, 48 steps, ONE persistent
// kernel. 6 phases x 8 substeps; boundaries sync the 3x3 tile neighborhood via
// agent-scope atomic flags. Halo exchange is FP16-packed QUADS: one
// global_{store,load}_dwordx4 sc0 sc1 (16B coherent, same cache-bypass flags
// as agent atomics) carries (C,P) x 4 row-adjacent cells -> half of r12's
// transaction count. Publish LDS-sourced lane-coalesced; pull batched into
// registers then b128 LDS writes. Protocol identical to r12.

typedef unsigned long long u64;
typedef __attribute__((ext_vector_type(4))) unsigned int u32x4;

#define GN     512
#define NMASK  511
#define NCH    16
#define NT     48
#define NM     128
#define WW     208            // window size
#define WOFF   103            // source offset inside window
#define TI     52             // tile interior
#define TS     8              // substeps per phase
#define NPHASE 6
#define HALO   16             // 2*TS
#define LT     84             // tile width (TI + 2*HALO)
#define LTS    84             // LDS row stride
#define LDSE   (LTS*LT)       // 7056
#define WCELLS (WW*WW)        // 43264
#define NTH    448            // 7 waves
#define NACT   441            // 21x21 threads x 4x4 cells = 84^2
#define NBLK   256
#define FQUAD  576            // frame cell-quads (2304/4)
#define FQUAD_A 416           // rows 16-31,52-67 x cols 16-67 (13 quads/row)
#define NQUAD  1088           // halo cell-quads (4352/4)
#define NQUAD_TB 672          // rows 0-15,68-83 x 21 quads/row
#define NPULLQ 3              // ceil(NQUAD / NTH)

__device__ __forceinline__ float4 ld4(const float* p) { return *(const float4*)p; }
__device__ __forceinline__ void st4(float* p, float4 v) { *(float4*)p = v; }
__device__ __forceinline__ float2 ld2(const float* p) { return *(const float2*)p; }

__device__ __forceinline__ unsigned pack2(float c, float p) {
    _Float16 hc = (_Float16)c, hp = (_Float16)p;
    unsigned short uc, up;
    __builtin_memcpy(&uc, &hc, 2); __builtin_memcpy(&up, &hp, 2);
    return (unsigned)uc | ((unsigned)up << 16);
}
__device__ __forceinline__ float2 unpack2(unsigned v) {   // -> (C, P)
    unsigned short uc = (unsigned short)(v & 0xffffu), up = (unsigned short)(v >> 16);
    _Float16 hc, hp;
    __builtin_memcpy(&hc, &uc, 2); __builtin_memcpy(&hp, &up, 2);
    return make_float2((float)hc, (float)hp);
}

// 16B coherent (cross-XCD) store/load: same sc0 sc1 flags as agent atomics.
__device__ __forceinline__ void st_coh(unsigned* p, u32x4 v) {
    asm volatile("global_store_dwordx4 %0, %1, off sc0 sc1"
                 :: "v"(p), "v"(v) : "memory");
}
__device__ __forceinline__ u32x4 ld_coh(const unsigned* p) {
    u32x4 r;
    asm volatile("global_load_dwordx4 %0, %1, off sc0 sc1"
                 : "=v"(r) : "v"(p) : "memory");
    return r;
}

__device__ __forceinline__ float kcoef(const float* __restrict__ x, int gi, int gj) {
    float xp;
    if (gi < 55 || gi >= 457 || gj < 55 || gj >= 457)
        xp = 1e-6f;                                   // ABC pad
    else if (gi >= 128 && gi < 384 && gj >= 128 && gj < 384)
        xp = x[(gi - 128) * 256 + (gj - 128)];
    else
        xp = 1.5f;                                    // bg pad
    float t = 0.2f * xp;
    return t * t;
}

// support-cone distance of a tile's 84^2 region to the source (channel-indep.)
__device__ __forceinline__ int tile_sdist(int ti, int tj) {
    int lo = ti * TI - HALO, hi = lo + LT - 1;
    int di = WOFF < lo ? lo - WOFF : (WOFF > hi ? WOFF - hi : 0);
    lo = tj * TI - HALO; hi = lo + LT - 1;
    int dj = WOFF < lo ? lo - WOFF : (WOFF > hi ? WOFF - hi : 0);
    return di > dj ? di : dj;
}
__device__ __forceinline__ bool tile_live(int ti, int tj, int ph) {
    return tile_sdist(ti, tj) <= 2 * (ph * TS + TS) + 4;
}

__global__ __launch_bounds__(NTH, 1)
void persist_kernel(const float* __restrict__ x,
                    const float* __restrict__ src,
                    const int* __restrict__ meas,
                    const int* __restrict__ trans,
                    int* __restrict__ flags,
                    unsigned* __restrict__ GA, unsigned* __restrict__ GB,
                    float* __restrict__ out)
{
    __shared__ float lds0[LDSE];
    __shared__ float lds1[LDSE];
    const int tid  = threadIdx.x;
    const int b    = blockIdx.x;
    const int r    = b & 15;          // channel
    const int tile = b >> 4;
    const int tI   = tile >> 2, tJ = tile & 3;
    const int ri0  = tI * TI - HALO;
    const int rj0  = tJ * TI - HALO;

    const bool active = tid < NACT;
    const int ty = tid / 21, tx = tid - 21 * (tid / 21);
    const int li0 = 4 * ty, lj0 = 4 * tx;
    const bool inner = active && tx >= 4 && tx <= 16 && ty >= 4 && ty <= 16;

    // zero BOTH buffers (dead->live blocks rely on pristine-zero LDS)
    for (int q = tid; q < LDSE / 4; q += NTH) {
        st4(&lds0[q * 4], make_float4(0.f, 0.f, 0.f, 0.f));
        st4(&lds1[q * 4], make_float4(0.f, 0.f, 0.f, 0.f));
    }

    const int trv = trans[r];
    const int ox = (trv >> 9) - WOFF, oy = (trv & NMASK) - WOFF;

    float C[16], P[16], K[16];
    #pragma unroll
    for (int i = 0; i < 16; ++i) { C[i] = 0.f; P[i] = 0.f; K[i] = 0.f; }

    int offT2 = 0, offT1 = 0, offB1 = 0, offB2 = 0;
    int offLp[4] = {0,0,0,0}, offRp[4] = {0,0,0,0}, offC[4] = {0,0,0,0};
    unsigned smask = 0;
    if (active) {
        #pragma unroll
        for (int rr = 0; rr < 4; ++rr) {
            int wr = ri0 + li0 + rr;
            #pragma unroll
            for (int cc = 0; cc < 4; ++cc) {
                int wc = rj0 + lj0 + cc;
                K[rr*4+cc] = kcoef(x, (ox + wr) & NMASK, (oy + wc) & NMASK);
            }
        }
        int rT2 = li0 - 2 < 0 ? 0 : li0 - 2;
        int rT1 = li0 - 1 < 0 ? 0 : li0 - 1;
        int rB1 = li0 + 4 > LT - 1 ? LT - 1 : li0 + 4;
        int rB2 = li0 + 5 > LT - 1 ? LT - 1 : li0 + 5;
        offT2 = rT2 * LTS + lj0;  offT1 = rT1 * LTS + lj0;
        offB1 = rB1 * LTS + lj0;  offB2 = rB2 * LTS + lj0;
        #pragma unroll
        for (int rr = 0; rr < 4; ++rr) {
            int base = (li0 + rr) * LTS + lj0;
            offC[rr] = base;
            int ol = base - 2;  if (ol < 0) ol = 0;           // 8B aligned
            int orr = base + 4; if (orr > LDSE - 2) orr = LDSE - 2;
            offLp[rr] = ol; offRp[rr] = orr;
        }
        int si = (WOFF - ri0) - li0, sj = (WOFF - rj0) - lj0;
        if (si >= 0 && si < 4 && sj >= 0 && sj < 4) smask = 1u << (si * 4 + sj);
    }

    bool mvalid = false; int mlds = 0; float* mout = nullptr;
    if (tid < NM) {
        int mc = meas[tid];
        int mi = ((mc >> 9)    - ox) & NMASK;
        int mj = ((mc & NMASK) - oy) & NMASK;
        int li = mi - ri0, lj = mj - rj0;
        mvalid = (li >= HALO && li < HALO + TI && lj >= HALO && lj < HALO + TI);
        mlds = li * LTS + lj;
        mout = out + (size_t)(r * NM + tid) * NT;
    }

    __syncthreads();

    auto step1 = [&](float (&A)[16], float (&B)[16],
                     const float* rd, float* wb, float sval, int jj) {
        if (active) {
            float t2[4], t1[4], b1a[4], b2a[4];
            float4 v;
            v = ld4(rd + offT2); t2[0]=v.x;  t2[1]=v.y;  t2[2]=v.z;  t2[3]=v.w;
            v = ld4(rd + offT1); t1[0]=v.x;  t1[1]=v.y;  t1[2]=v.z;  t1[3]=v.w;
            v = ld4(rd + offB1); b1a[0]=v.x; b1a[1]=v.y; b1a[2]=v.z; b1a[3]=v.w;
            v = ld4(rd + offB2); b2a[0]=v.x; b2a[1]=v.y; b2a[2]=v.z; b2a[3]=v.w;
            float2 lp[4], rp[4];
            #pragma unroll
            for (int rr = 0; rr < 4; ++rr) {
                lp[rr] = ld2(rd + offLp[rr]);   // cols -2,-1
                rp[rr] = ld2(rd + offRp[rr]);   // cols +4,+5
            }
            #pragma unroll
            for (int rr = 0; rr < 4; ++rr) {
                float h[8];
                h[0]=lp[rr].x; h[1]=lp[rr].y;
                h[2]=B[rr*4+0]; h[3]=B[rr*4+1]; h[4]=B[rr*4+2]; h[5]=B[rr*4+3];
                h[6]=rp[rr].x; h[7]=rp[rr].y;
                #pragma unroll
                for (int cc = 0; cc < 4; ++cc) {
                    float vm2 = (rr == 0) ? t2[cc]  : (rr == 1) ? t1[cc]  : B[(rr-2)*4+cc];
                    float vm1 = (rr == 0) ? t1[cc]  : B[(rr-1)*4+cc];
                    float vp1 = (rr == 3) ? b1a[cc] : B[(rr+1)*4+cc];
                    float vp2 = (rr == 3) ? b2a[cc] : (rr == 2) ? b1a[cc] : B[(rr+2)*4+cc];
                    float c0  = h[cc+2];
                    float lap = (16.f * (h[cc+1] + h[cc+3] + vm1 + vp1)
                                 - (h[cc] + h[cc+4] + vm2 + vp2)
                                 - 60.f * c0) * (1.f / 12.f);
                    float pn = 2.f * c0 - A[rr*4+cc] + K[rr*4+cc] * lap;
                    if (smask & (1u << (rr*4+cc))) pn += sval;
                    A[rr*4+cc] = pn;
                }
                st4(wb + offC[rr],
                    make_float4(A[rr*4+0], A[rr*4+1], A[rr*4+2], A[rr*4+3]));
            }
        }
        __syncthreads();
        if (mvalid) mout[jj] = wb[mlds];
    };

    for (int ph = 0; ph < NPHASE; ++ph) {
        const int J = ph * TS;
        const bool liveSelf = tile_live(tI, tJ, ph);
        unsigned* Wp = ((ph & 1) ? GB : GA) + (size_t)r * WCELLS;
        const bool bnd = ph < NPHASE - 1;
        if (liveSelf) {
            float sv[TS];
            #pragma unroll
            for (int s = 0; s < TS; ++s) sv[s] = 0.09f * src[J + s];
            step1(P, C, lds0, lds1, sv[0], J + 0);
            step1(C, P, lds1, lds0, sv[1], J + 1);
            step1(P, C, lds0, lds1, sv[2], J + 2);
            step1(C, P, lds1, lds0, sv[3], J + 3);
            step1(P, C, lds0, lds1, sv[4], J + 4);
            step1(C, P, lds1, lds0, sv[5], J + 5);
            step1(P, C, lds0, lds1, sv[6], J + 6);
            step1(C, P, lds1, lds0, sv[7], J + 7);
            // lds0 = f_{J+7} (valid [16,68)^2), lds1 = f_{J+6}
        }
        if (bnd) {
            if (liveSelf) {   // publish frame as fp16-packed cell QUADS (16B)
                for (int pf = tid; pf < FQUAD; pf += NTH) {
                    int row, col;
                    if (pf < FQUAD_A) {
                        int rA = pf / 13;
                        row = 16 + (rA < 16 ? rA : rA + 20);
                        col = 16 + 4 * (pf - 13 * rA);
                    } else {
                        int p2 = pf - FQUAD_A;
                        int rB = p2 >> 3;
                        int c  = p2 & 7;
                        row = 32 + rB;
                        col = c < 4 ? 16 + 4 * c : 4 * c + 36;   // 52..64
                    }
                    int l = row * LTS + col;
                    u32x4 v;
                    v.x = pack2(lds0[l],     lds1[l]);
                    v.y = pack2(lds0[l + 1], lds1[l + 1]);
                    v.z = pack2(lds0[l + 2], lds1[l + 2]);
                    v.w = pack2(lds0[l + 3], lds1[l + 3]);
                    int gw = (ri0 + row) * WW + (rj0 + col);     // %4 == 0
                    st_coh(&Wp[gw], v);
                }
                asm volatile("s_waitcnt vmcnt(0)" ::: "memory");
            }
            __syncthreads();
            if (liveSelf && tid == 0)
                __hip_atomic_store(&flags[ph * NBLK + b], 1,
                                   __ATOMIC_RELAXED, __HIP_MEMORY_SCOPE_AGENT);
            const bool liveNext = tile_live(tI, tJ, ph + 1);
            if (liveNext && tid < 9 && tid != 4) {     // spin on live neighbors
                int nti = tI + tid / 3 - 1, ntj = tJ + tid % 3 - 1;
                if ((unsigned)nti < 4u && (unsigned)ntj < 4u &&
                    tile_live(nti, ntj, ph)) {
                    int* f = &flags[ph * NBLK + ((((nti << 2) | ntj) << 4) | r)];
                    while (!__hip_atomic_load(f, __ATOMIC_RELAXED,
                                              __HIP_MEMORY_SCOPE_AGENT)) {}
                }
            }
            __syncthreads();
            if (liveNext) {
                // batched pull of halo quads (static reg indices), then LDS b128
                u32x4 vv[NPULLQ]; int ll[NPULLQ];
                #pragma unroll
                for (int k = 0; k < NPULLQ; ++k) {
                    vv[k].x = vv[k].y = vv[k].z = vv[k].w = 0u; ll[k] = -1;
                    int p = tid + k * NTH;
                    if (p < NQUAD) {
                        int row, col;
                        if (p < NQUAD_TB) {
                            int rT = p / 21;
                            row = rT < 16 ? rT : rT + 52;
                            col = 4 * (p - 21 * rT);
                        } else {
                            int p2 = p - NQUAD_TB;
                            int rM = p2 >> 3;
                            int c  = p2 & 7;
                            row = 16 + rM;
                            col = c < 4 ? 4 * c : 4 * c + 52;    // 68..80
                        }
                        ll[k] = row * LTS + col;
                        int nti = tI + (row < HALO ? -1 : (row >= HALO + TI ? 1 : 0));
                        int ntj = tJ + (col < HALO ? -1 : (col >= HALO + TI ? 1 : 0));
                        if ((unsigned)nti < 4u && (unsigned)ntj < 4u &&
                            tile_live(nti, ntj, ph)) {
                            int gw = (ri0 + row) * WW + (rj0 + col);
                            vv[k] = ld_coh(&Wp[gw]);
                        } else {
                            ll[k] = -ll[k] - 2;   // mark zero-fill (encode)
                        }
                    }
                }
                asm volatile("s_waitcnt vmcnt(0)" ::: "memory");
                #pragma unroll
                for (int k = 0; k < NPULLQ; ++k) {
                    int l = ll[k];
                    bool zf = false;
                    if (l < -1) { l = -l - 2; zf = true; }
                    if (l >= 0) {
                        float4 f0, f1;
                        if (zf) {
                            f0 = make_float4(0.f,0.f,0.f,0.f); f1 = f0;
                        } else {
                            float2 a = unpack2(vv[k].x), bq = unpack2(vv[k].y);
                            float2 c2 = unpack2(vv[k].z), d = unpack2(vv[k].w);
                            f0 = make_float4(a.x, bq.x, c2.x, d.x);
                            f1 = make_float4(a.y, bq.y, c2.y, d.y);
                        }
                        st4(&lds0[l], f0);
                        st4(&lds1[l], f1);
                    }
                }
                __syncthreads();
                if (active && !inner) {   // ring threads refill regs from LDS
                    #pragma unroll
                    for (int rr = 0; rr < 4; ++rr) {
                        float4 vc = ld4(&lds0[offC[rr]]);
                        float4 vp = ld4(&lds1[offC[rr]]);
                        C[rr*4+0]=vc.x; C[rr*4+1]=vc.y; C[rr*4+2]=vc.z; C[rr*4+3]=vc.w;
                        P[rr*4+0]=vp.x; P[rr*4+1]=vp.y; P[rr*4+2]=vp.z; P[rr*4+3]=vp.w;
                    }
                }
            }
        }
    }
}

extern "C" void kernel_launch(void* const* d_in, const int* in_sizes, int n_in,
                              void* d_out, int out_size, void* d_ws, size_t ws_size,
                              hipStream_t stream)
{
    const float* x     = (const float*)d_in[0];
    const float* src   = (const float*)d_in[1];
    const int*   meas  = (const int*)d_in[2];
    const int*   trans = (const int*)d_in[3];
    float* outp = (float*)d_out;

    int*      flags = (int*)d_ws;                       // NPHASE*NBLK ints
    unsigned* GA = (unsigned*)((char*)d_ws + 8192);     // 16B-aligned
    unsigned* GB = GA + (size_t)NCH * WCELLS;

    hipMemsetAsync(flags, 0, NPHASE * NBLK * sizeof(int), stream);
    hipMemsetAsync(outp, 0, (size_t)out_size * sizeof(float), stream);

    persist_kernel<<<NBLK, NTH, 0, stream>>>(x, src, meas, trans, flags,
                                             GA, GB, outp);
}